// Round 1
// 340.996 us; speedup vs baseline: 1.0796x; 1.0796x over previous
//
#include <hip/hip_runtime.h>

#define BB 16
#define CC 128
#define NN 16384
#define BN_EPS 1e-5f

typedef unsigned short u16;
typedef short short8 __attribute__((ext_vector_type(8)));
typedef float floatx4 __attribute__((ext_vector_type(4)));

__device__ inline float b2f(u16 u) {
    union { unsigned int i; float f; } c; c.i = ((unsigned int)u) << 16; return c.f;
}
__device__ inline u16 f2b(float f) {  // round-to-nearest-even bf16
    union { float f; unsigned int i; } c; c.f = f;
    unsigned int r = c.i + 0x7fffu + ((c.i >> 16) & 1u);
    return (u16)(r >> 16);
}

// ---------------------------------------------------------------------------
// K1: Gram via split-bf16 MFMA (E ~= XhXh^T + XlXh^T + XhXl^T), atomicAdd
//     straight into energy. S[b][j] = sum_n x (register-accumulated).
//
// Redesign vs previous round:
//  * Each block now computes a 64-row x 128-col half-Gram over a K-slab of
//    512 (8 stages of 64). Grid stays 1024 (= 16 b x 2 rowhalf x 32 kchunk),
//    4 blocks/CU; atomics per element halve (32 contributions, not 64).
//  * Register prefetch pipeline: next stage's 8 float4 are loaded inside the
//    convert loop; raw s_barrier + lgkmcnt(0) instead of __syncthreads so the
//    in-flight vmcnt loads survive the barriers (HIP's __syncthreads drains
//    vmcnt(0) and would serialize the pipeline).
//  * acc shrinks 64->32 regs, making room for 32 prefetch regs within the
//    128-reg budget of __launch_bounds__(256,4).
//  * XCD swizzle: all 64 blocks of a batch land on one XCD (atomic L2
//    locality); rowhalf pairs sharing an x-slab are adjacent on that XCD.
// LDS 2 x 128x72 halfs = 36.9 KB -> 4 blocks/CU (16 waves/CU).
// ---------------------------------------------------------------------------
#define K1_LD 72   // 64 + 8 halfs pad (144 B rows, 16B-aligned)
__global__ __launch_bounds__(256, 4) void k_gram(const float* __restrict__ x,
                                                 float* __restrict__ energy,
                                                 float* __restrict__ S)
{
    __shared__ u16 th[128 * K1_LD];
    __shared__ u16 tl[128 * K1_LD];
    const int rbid = blockIdx.x;
    const int xcd  = rbid & 7;                // dispatch round-robins XCDs
    const int li   = rbid >> 3;               // 0..127 within XCD
    const int b    = xcd + 8 * (li >> 6);     // 2 batches per XCD
    const int sub  = li & 63;
    const int rowhalf = sub & 1;              // which 64 output rows
    const int k0   = (sub >> 1) * 512;        // K-slab of 512
    const int t    = threadIdx.x;
    const int w = t >> 6, lane = t & 63, quad = lane >> 4, colL = lane & 15;

    floatx4 acc[8];
#pragma unroll
    for (int ct = 0; ct < 8; ++ct) acc[ct] = {0.f, 0.f, 0.f, 0.f};
    float rs[8];
#pragma unroll
    for (int it = 0; it < 8; ++it) rs[it] = 0.f;

    const float* xb = x + (size_t)b * CC * NN;
    const int rrow = t >> 4;        // thread's fixed row residue (0..15)
    const int c4   = t & 15;        // thread's fixed col slot

    // prologue: stage-0 loads into registers
    float4 v[8];
#pragma unroll
    for (int it = 0; it < 8; ++it)
        v[it] = *(const float4*)(xb + (size_t)(it * 16 + rrow) * NN + k0 + c4 * 4);

    const int arow = rowhalf * 64 + w * 16 + colL;   // this wave's A rows
    for (int s = 0; s < 8; ++s) {
        // convert + LDS write current stage; issue next stage's loads in the
        // same loop so they fly across both barriers + the MFMA phase
#pragma unroll
        for (int it = 0; it < 8; ++it) {
            const int row = it * 16 + rrow;
            float4 vv = v[it];
            if (s < 7)
                v[it] = *(const float4*)(xb + (size_t)row * NN + k0 + (s + 1) * 64 + c4 * 4);
            u16 h0 = f2b(vv.x), h1 = f2b(vv.y), h2 = f2b(vv.z), h3 = f2b(vv.w);
            uint2 hv, lv;
            hv.x = (unsigned)h0 | ((unsigned)h1 << 16);
            hv.y = (unsigned)h2 | ((unsigned)h3 << 16);
            lv.x = (unsigned)f2b(vv.x - b2f(h0)) | ((unsigned)f2b(vv.y - b2f(h1)) << 16);
            lv.y = (unsigned)f2b(vv.z - b2f(h2)) | ((unsigned)f2b(vv.w - b2f(h3)) << 16);
            *(uint2*)&th[row * K1_LD + c4 * 4] = hv;
            *(uint2*)&tl[row * K1_LD + c4 * 4] = lv;
            rs[it] += (vv.x + vv.y) + (vv.z + vv.w);
        }
        // raw barrier: ds_writes drained (lgkmcnt), vmcnt prefetch NOT drained
        asm volatile("s_waitcnt lgkmcnt(0)" ::: "memory");
        __builtin_amdgcn_s_barrier();

#pragma unroll
        for (int ks2 = 0; ks2 < 2; ++ks2) {
            const int kk = ks2 * 32 + quad * 8;
            short8 ah = *(const short8*)&th[arow * K1_LD + kk];
            short8 al = *(const short8*)&tl[arow * K1_LD + kk];
#pragma unroll
            for (int ct = 0; ct < 8; ++ct) {
                short8 bh = *(const short8*)&th[(ct * 16 + colL) * K1_LD + kk];
                short8 bl = *(const short8*)&tl[(ct * 16 + colL) * K1_LD + kk];
                acc[ct] = __builtin_amdgcn_mfma_f32_16x16x32_bf16(ah, bh, acc[ct], 0, 0, 0);
                acc[ct] = __builtin_amdgcn_mfma_f32_16x16x32_bf16(al, bh, acc[ct], 0, 0, 0);
                acc[ct] = __builtin_amdgcn_mfma_f32_16x16x32_bf16(ah, bl, acc[ct], 0, 0, 0);
            }
        }
        // raw barrier: my ds_reads done before anyone overwrites the tile
        asm volatile("s_waitcnt lgkmcnt(0)" ::: "memory");
        __builtin_amdgcn_s_barrier();
    }

    // accumulate half-Gram tile (C/D layout: col=lane&15, row=quad*4+r)
    float* eb = energy + b * CC * CC;
    const int erow = rowhalf * 64 + w * 16 + quad * 4;
#pragma unroll
    for (int ct = 0; ct < 8; ++ct)
#pragma unroll
        for (int r = 0; r < 4; ++r)
            atomicAdd(&eb[(erow + r) * CC + ct * 16 + colL], acc[ct][r]);

    // row-sums: only rowhalf-0 blocks contribute (they cover every staged row
    // of their K-slab exactly once)
    if (rowhalf == 0) {
#pragma unroll
        for (int it = 0; it < 8; ++it) {
            float ps = rs[it];
#pragma unroll
            for (int off = 8; off > 0; off >>= 1) ps += __shfl_down(ps, off, 16);
            if (colL == 0) atomicAdd(&S[b * CC + it * 16 + w * 4 + quad], ps);
        }
    }
}

// ---------------------------------------------------------------------------
// K2: per (b,i): att = softmax(-E[i,:]), store bf16;
//     meanacc[i] += sum_j att_j S[b,j];  e2acc[i] += att^T E att
// grid 2048 = 16*128, block 256
// ---------------------------------------------------------------------------
__global__ __launch_bounds__(256) void k_soft(const float* __restrict__ energy,
                                              const float* __restrict__ S,
                                              u16* __restrict__ attb,
                                              float* __restrict__ meanacc,
                                              float* __restrict__ e2acc)
{
    const int b = blockIdx.x >> 7;
    const int i = blockIdx.x & 127;
    const int t = threadIdx.x;
    __shared__ float att[128];
    __shared__ float red[256];
    const float* E = energy + b * CC * CC;

    float e = (t < 128) ? E[i * CC + t] : 3.0e38f;
    red[t] = e; __syncthreads();
    for (int s2 = 128; s2 > 0; s2 >>= 1) { if (t < s2) red[t] = fminf(red[t], red[t + s2]); __syncthreads(); }
    float emin = red[0]; __syncthreads();

    float a = (t < 128) ? expf(emin - e) : 0.f;
    red[t] = a; __syncthreads();
    for (int s2 = 128; s2 > 0; s2 >>= 1) { if (t < s2) red[t] += red[t + s2]; __syncthreads(); }
    float Z = red[0]; __syncthreads();

    float attf = 0.f;
    if (t < 128) {
        u16 ab = f2b(a / Z);
        attf = b2f(ab);                       // bf16-rounded: self-consistent with K3's MFMA
        attb[((size_t)b * CC + i) * CC + t] = ab;
        att[t] = attf;
    }
    float mp = (t < 128) ? attf * S[b * CC + t] : 0.f;
    red[t] = mp; __syncthreads();
    for (int s2 = 128; s2 > 0; s2 >>= 1) { if (t < s2) red[t] += red[t + s2]; __syncthreads(); }
    if (t == 0) atomicAdd(&meanacc[i], red[0]);
    __syncthreads();

    // e2 = sum_j att_j * (sum_k att_k E[j][k])
    const int j    = t & 127;
    const int half = t >> 7;
    const float* Ej = E + j * CC + half * 64;
    float inner = 0.f;
#pragma unroll 8
    for (int k = 0; k < 64; ++k) inner += att[half * 64 + k] * Ej[k];
    red[t] = inner; __syncthreads();
    float contrib = (t < 128) ? (red[t] + red[t + 128]) * att[t] : 0.f;
    __syncthreads();
    red[t] = contrib; __syncthreads();
    for (int s2 = 128; s2 > 0; s2 >>= 1) { if (t < s2) red[t] += red[t + s2]; __syncthreads(); }
    if (t == 0) atomicAdd(&e2acc[i], red[0]);
}

// ---------------------------------------------------------------------------
// K3: out = alpha_c * (att @ q_bf16) + beta_c + x.
// q staged TRANSPOSED (n-major) via register 4x4 transpose, rotation-swizzled
// so B-fragments are aligned ds_read_b128. att A-frags read from global (L1/L2
// hot: 32 KB/batch shared by 128 blocks). LDS 35.8 KB -> 4 blocks/CU.
// grid 2048 = 16 batches x 128 n-chunks of 128, block 256
// ---------------------------------------------------------------------------
#define K3_LD 136   // k-extent 128 + 8 pad (272 B rows, 16B-aligned)
__global__ __launch_bounds__(256, 4) void k_out(const float* __restrict__ x,
                                                const u16* __restrict__ attb,
                                                const float* __restrict__ meanacc,
                                                const float* __restrict__ e2acc,
                                                const float* __restrict__ gamma,
                                                const float* __restrict__ bnw,
                                                const float* __restrict__ bnb,
                                                float* __restrict__ out)
{
    __shared__ u16 qT[128 * K3_LD];   // [n][k], k-group rotated by n
    __shared__ float alpha[128];
    __shared__ float beta[128];
    const int b   = blockIdx.x >> 7;
    const int nn0 = (blockIdx.x & 127) * 128;
    const int t   = threadIdx.x;

    if (t < 128) {
        float g   = gamma[0];
        const float invBN = 1.f / (float)(BB * NN);
        float m   = g * meanacc[t] * invBN;
        float e2  = g * g * e2acc[t] * invBN;
        float var = e2 - m * m;
        float inv = rsqrtf(var + BN_EPS);
        float wv  = bnw[t];
        alpha[t] = g * wv * inv;
        beta[t]  = bnb[t] - m * wv * inv;
    }

    const float* xb = x + (size_t)b * CC * NN + nn0;
    const int n0 = (t & 31) * 4;
#pragma unroll
    for (int rep = 0; rep < 4; ++rep) {
        const int c0 = ((t >> 5) + rep * 8) * 4;   // k-rows c0..c0+3
        float4 f0 = *(const float4*)(xb + (size_t)(c0 + 0) * NN + n0);
        float4 f1 = *(const float4*)(xb + (size_t)(c0 + 1) * NN + n0);
        float4 f2 = *(const float4*)(xb + (size_t)(c0 + 2) * NN + n0);
        float4 f3 = *(const float4*)(xb + (size_t)(c0 + 3) * NN + n0);
        const float fx[4] = {f0.x, f1.x, f2.x, f3.x};
        const float fy[4] = {f0.y, f1.y, f2.y, f3.y};
        const float fz[4] = {f0.z, f1.z, f2.z, f3.z};
        const float fw[4] = {f0.w, f1.w, f2.w, f3.w};
        const float* cols[4] = {fx, fy, fz, fw};
#pragma unroll
        for (int jn = 0; jn < 4; ++jn) {           // n = n0+jn: halfs k=c0..c0+3
            int n = n0 + jn;
            int g = ((c0 >> 3) + n) & 15;
            uint2 v;
            v.x = (unsigned)f2b(cols[jn][0]) | ((unsigned)f2b(cols[jn][1]) << 16);
            v.y = (unsigned)f2b(cols[jn][2]) | ((unsigned)f2b(cols[jn][3]) << 16);
            *(uint2*)&qT[n * K3_LD + g * 8 + (c0 & 7)] = v;
        }
    }
    __syncthreads();

    const int w = t >> 6, lane = t & 63, quad = lane >> 4, colL = lane & 15;
    const u16* ag = attb + (size_t)b * CC * CC;
    floatx4 acc[8][2];
#pragma unroll
    for (int rt = 0; rt < 8; ++rt) { acc[rt][0] = {0.f,0.f,0.f,0.f}; acc[rt][1] = {0.f,0.f,0.f,0.f}; }

#pragma unroll
    for (int ks = 0; ks < 4; ++ks) {
        const int kk = ks * 32 + quad * 8;
        const int n_a = w * 32 + colL;
        const int n_b = n_a + 16;
        short8 bf0 = *(const short8*)&qT[n_a * K3_LD + ((((kk) >> 3) + n_a) & 15) * 8];
        short8 bf1 = *(const short8*)&qT[n_b * K3_LD + ((((kk) >> 3) + n_b) & 15) * 8];
#pragma unroll
        for (int rt = 0; rt < 8; ++rt) {
            short8 af = *(const short8*)&ag[(rt * 16 + colL) * CC + kk];   // L1-hot
            acc[rt][0] = __builtin_amdgcn_mfma_f32_16x16x32_bf16(af, bf0, acc[rt][0], 0, 0, 0);
            acc[rt][1] = __builtin_amdgcn_mfma_f32_16x16x32_bf16(af, bf1, acc[rt][1], 0, 0, 0);
        }
    }

    float* ob = out + (size_t)b * CC * NN + nn0;
#pragma unroll
    for (int rt = 0; rt < 8; ++rt)
#pragma unroll
        for (int ct = 0; ct < 2; ++ct)
#pragma unroll
            for (int r = 0; r < 4; ++r) {
                int chn = rt * 16 + quad * 4 + r;
                int nn  = w * 32 + ct * 16 + colL;
                float v = alpha[chn] * acc[rt][ct][r] + beta[chn]
                        + xb[(size_t)chn * NN + nn];   // residual fp32 (L1-hot re-read)
                ob[(size_t)chn * NN + nn] = v;
            }
}

// ---------------------------------------------------------------------------
// ws layout (bytes):
//   [0,       1048576)  energy  fp32 [16][128][128]  (atomic-accumulated)
//   [1048576, 1056768)  S       fp32 [16][128]
//   [1056768, 1057280)  meanacc fp32 [128]
//   [1057280, 1057792)  e2acc   fp32 [128]
//   [1057792, 1582080)  attb    bf16 [16][128][128]
// ---------------------------------------------------------------------------
extern "C" void kernel_launch(void* const* d_in, const int* in_sizes, int n_in,
                              void* d_out, int out_size, void* d_ws, size_t ws_size,
                              hipStream_t stream)
{
    const float* x     = (const float*)d_in[0];
    const float* gamma = (const float*)d_in[1];
    const float* bnw   = (const float*)d_in[2];
    const float* bnb   = (const float*)d_in[3];
    float* out = (float*)d_out;

    char* ws = (char*)d_ws;
    float* energy  = (float*)(ws);
    float* S       = (float*)(ws + 1048576);
    float* meanacc = (float*)(ws + 1056768);
    float* e2acc   = (float*)(ws + 1057280);
    u16*   attb    = (u16*)(ws + 1057792);

    hipMemsetAsync(ws, 0, 1057792, stream);   // zero energy/S/accumulators
    hipLaunchKernelGGL(k_gram, dim3(1024), dim3(256), 0, stream, x, energy, S);
    hipLaunchKernelGGL(k_soft, dim3(2048), dim3(256), 0, stream, energy, S, attb, meanacc, e2acc);
    hipLaunchKernelGGL(k_out,  dim3(2048), dim3(256), 0, stream, x, attb, meanacc, e2acc, gamma, bnw, bnb, out);
}

// Round 2
// 339.301 us; speedup vs baseline: 1.0850x; 1.0050x over previous
//
#include <hip/hip_runtime.h>

#define BB 16
#define CC 128
#define NN 16384
#define BN_EPS 1e-5f

typedef unsigned short u16;
typedef short short8 __attribute__((ext_vector_type(8)));
typedef float floatx4 __attribute__((ext_vector_type(4)));

__device__ inline float b2f(u16 u) {
    union { unsigned int i; float f; } c; c.i = ((unsigned int)u) << 16; return c.f;
}
__device__ inline u16 f2b(float f) {  // round-to-nearest-even bf16
    union { float f; unsigned int i; } c; c.f = f;
    unsigned int r = c.i + 0x7fffu + ((c.i >> 16) & 1u);
    return (u16)(r >> 16);
}

// ---------------------------------------------------------------------------
// K1: Gram via split-bf16 MFMA (E ~= XhXh^T + XlXh^T + XhXl^T), atomicAdd
//     straight into energy. S[b][j] = sum_n x (register-accumulated).
//
// Round-2 redesign: one block = FULL 128x128 Gram tile over a K-slab of 512.
//  * 512-thread / 8-wave blocks, waves partitioned 4 row-pairs x 2 col-halves:
//    each wave computes 32 rows x 64 cols (acc 2x4 floatx4 = 32 AGPRs).
//  * Eliminates r1's rowhalf duplication: staging fetch back to 1x (134 MB),
//    convert VALU per element halved, LDS reads per output ~halved.
//  * grid 512 = 16 b x 32 slabs -> 2 blocks/CU x 8 waves = 16 waves/CU.
//  * Atomics: 512 blocks x 64 KB = 34 MB (vs 43.5 in r1).
//  * Same register-prefetch pipeline with raw s_barrier (vmcnt NOT drained
//    across barriers) that produced the r1 win.
// LDS 2 x 128x72 halfs = 36.9 KB -> 2 blocks/CU fits easily.
// ---------------------------------------------------------------------------
#define K1_LD 72   // 64 + 8 halfs pad (144 B rows, 16B-aligned)
__global__ __launch_bounds__(512, 4) void k_gram(const float* __restrict__ x,
                                                 float* __restrict__ energy,
                                                 float* __restrict__ S)
{
    __shared__ u16 th[128 * K1_LD];
    __shared__ u16 tl[128 * K1_LD];
    const int rbid = blockIdx.x;              // 0..511
    const int xcd  = rbid & 7;                // dispatch round-robins XCDs
    const int li   = rbid >> 3;               // 0..63 within XCD
    const int b    = xcd * 2 + (li >> 5);     // 2 batches per XCD (atomic L2 locality)
    const int k0   = (li & 31) * 512;         // K-slab of 512
    const int t    = threadIdx.x;
    const int w = t >> 6, lane = t & 63, quad = lane >> 4, colL = lane & 15;
    const int w2 = w >> 1;                    // row-pair group (0..3)
    const int chf = w & 1;                    // col half (0..1)

    floatx4 acc[2][4];
#pragma unroll
    for (int rt = 0; rt < 2; ++rt)
#pragma unroll
        for (int ct = 0; ct < 4; ++ct) acc[rt][ct] = {0.f, 0.f, 0.f, 0.f};
    float rs[4];
#pragma unroll
    for (int it = 0; it < 4; ++it) rs[it] = 0.f;

    const float* xb = x + (size_t)b * CC * NN;
    const int rrow = t >> 4;        // thread's fixed row residue (0..31)
    const int c4   = t & 15;        // thread's fixed col slot

    // prologue: stage-0 loads into registers
    float4 v[4];
#pragma unroll
    for (int it = 0; it < 4; ++it)
        v[it] = *(const float4*)(xb + (size_t)(it * 32 + rrow) * NN + k0 + c4 * 4);

    const int arow0 = w2 * 32 + colL;         // this wave's A rows
    for (int s = 0; s < 8; ++s) {
        // convert + LDS write current stage; issue next stage's loads in the
        // same loop so they fly across both barriers + the MFMA phase
#pragma unroll
        for (int it = 0; it < 4; ++it) {
            const int row = it * 32 + rrow;
            float4 vv = v[it];
            if (s < 7)
                v[it] = *(const float4*)(xb + (size_t)row * NN + k0 + (s + 1) * 64 + c4 * 4);
            u16 h0 = f2b(vv.x), h1 = f2b(vv.y), h2 = f2b(vv.z), h3 = f2b(vv.w);
            uint2 hv, lv;
            hv.x = (unsigned)h0 | ((unsigned)h1 << 16);
            hv.y = (unsigned)h2 | ((unsigned)h3 << 16);
            lv.x = (unsigned)f2b(vv.x - b2f(h0)) | ((unsigned)f2b(vv.y - b2f(h1)) << 16);
            lv.y = (unsigned)f2b(vv.z - b2f(h2)) | ((unsigned)f2b(vv.w - b2f(h3)) << 16);
            *(uint2*)&th[row * K1_LD + c4 * 4] = hv;
            *(uint2*)&tl[row * K1_LD + c4 * 4] = lv;
            rs[it] += (vv.x + vv.y) + (vv.z + vv.w);
        }
        // raw barrier: ds_writes drained (lgkmcnt), vmcnt prefetch NOT drained
        asm volatile("s_waitcnt lgkmcnt(0)" ::: "memory");
        __builtin_amdgcn_s_barrier();

#pragma unroll
        for (int ks2 = 0; ks2 < 2; ++ks2) {
            const int kk = ks2 * 32 + quad * 8;
            short8 a0h = *(const short8*)&th[(arow0)      * K1_LD + kk];
            short8 a0l = *(const short8*)&tl[(arow0)      * K1_LD + kk];
            short8 a1h = *(const short8*)&th[(arow0 + 16) * K1_LD + kk];
            short8 a1l = *(const short8*)&tl[(arow0 + 16) * K1_LD + kk];
#pragma unroll
            for (int ct = 0; ct < 4; ++ct) {
                const int brow = chf * 64 + ct * 16 + colL;
                short8 bh = *(const short8*)&th[brow * K1_LD + kk];
                short8 bl = *(const short8*)&tl[brow * K1_LD + kk];
                acc[0][ct] = __builtin_amdgcn_mfma_f32_16x16x32_bf16(a0h, bh, acc[0][ct], 0, 0, 0);
                acc[1][ct] = __builtin_amdgcn_mfma_f32_16x16x32_bf16(a1h, bh, acc[1][ct], 0, 0, 0);
                acc[0][ct] = __builtin_amdgcn_mfma_f32_16x16x32_bf16(a0l, bh, acc[0][ct], 0, 0, 0);
                acc[1][ct] = __builtin_amdgcn_mfma_f32_16x16x32_bf16(a1l, bh, acc[1][ct], 0, 0, 0);
                acc[0][ct] = __builtin_amdgcn_mfma_f32_16x16x32_bf16(a0h, bl, acc[0][ct], 0, 0, 0);
                acc[1][ct] = __builtin_amdgcn_mfma_f32_16x16x32_bf16(a1h, bl, acc[1][ct], 0, 0, 0);
            }
        }
        // raw barrier: my ds_reads done before anyone overwrites the tile
        asm volatile("s_waitcnt lgkmcnt(0)" ::: "memory");
        __builtin_amdgcn_s_barrier();
    }

    // accumulate full Gram tile (C/D layout: col=lane&15, row=quad*4+r)
    float* eb = energy + b * CC * CC;
#pragma unroll
    for (int rt = 0; rt < 2; ++rt)
#pragma unroll
        for (int ct = 0; ct < 4; ++ct)
#pragma unroll
            for (int r = 0; r < 4; ++r) {
                int row = w2 * 32 + rt * 16 + quad * 4 + r;
                int col = chf * 64 + ct * 16 + colL;
                atomicAdd(&eb[row * CC + col], acc[rt][ct][r]);
            }

    // row-sums: every block contributes its K-slab's partial; rows staged once
#pragma unroll
    for (int it = 0; it < 4; ++it) {
        float ps = rs[it];
#pragma unroll
        for (int off = 8; off > 0; off >>= 1) ps += __shfl_down(ps, off, 16);
        if (c4 == 0) atomicAdd(&S[b * CC + it * 32 + rrow], ps);
    }
}

// ---------------------------------------------------------------------------
// K2: per (b,i): att = softmax(-E[i,:]), store bf16;
//     meanacc[i] += sum_j att_j S[b,j];  e2acc[i] += att^T E att
// grid 2048 = 16*128, block 256
// ---------------------------------------------------------------------------
__global__ __launch_bounds__(256) void k_soft(const float* __restrict__ energy,
                                              const float* __restrict__ S,
                                              u16* __restrict__ attb,
                                              float* __restrict__ meanacc,
                                              float* __restrict__ e2acc)
{
    const int b = blockIdx.x >> 7;
    const int i = blockIdx.x & 127;
    const int t = threadIdx.x;
    __shared__ float att[128];
    __shared__ float red[256];
    const float* E = energy + b * CC * CC;

    float e = (t < 128) ? E[i * CC + t] : 3.0e38f;
    red[t] = e; __syncthreads();
    for (int s2 = 128; s2 > 0; s2 >>= 1) { if (t < s2) red[t] = fminf(red[t], red[t + s2]); __syncthreads(); }
    float emin = red[0]; __syncthreads();

    float a = (t < 128) ? expf(emin - e) : 0.f;
    red[t] = a; __syncthreads();
    for (int s2 = 128; s2 > 0; s2 >>= 1) { if (t < s2) red[t] += red[t + s2]; __syncthreads(); }
    float Z = red[0]; __syncthreads();

    float attf = 0.f;
    if (t < 128) {
        u16 ab = f2b(a / Z);
        attf = b2f(ab);                       // bf16-rounded: self-consistent with K3's MFMA
        attb[((size_t)b * CC + i) * CC + t] = ab;
        att[t] = attf;
    }
    float mp = (t < 128) ? attf * S[b * CC + t] : 0.f;
    red[t] = mp; __syncthreads();
    for (int s2 = 128; s2 > 0; s2 >>= 1) { if (t < s2) red[t] += red[t + s2]; __syncthreads(); }
    if (t == 0) atomicAdd(&meanacc[i], red[0]);
    __syncthreads();

    // e2 = sum_j att_j * (sum_k att_k E[j][k])
    const int j    = t & 127;
    const int half = t >> 7;
    const float* Ej = E + j * CC + half * 64;
    float inner = 0.f;
#pragma unroll 8
    for (int k = 0; k < 64; ++k) inner += att[half * 64 + k] * Ej[k];
    red[t] = inner; __syncthreads();
    float contrib = (t < 128) ? (red[t] + red[t + 128]) * att[t] : 0.f;
    __syncthreads();
    red[t] = contrib; __syncthreads();
    for (int s2 = 128; s2 > 0; s2 >>= 1) { if (t < s2) red[t] += red[t + s2]; __syncthreads(); }
    if (t == 0) atomicAdd(&e2acc[i], red[0]);
}

// ---------------------------------------------------------------------------
// K3: out = alpha_c * (att @ q_bf16) + beta_c + x.
// q staged TRANSPOSED (n-major) via register 4x4 transpose, rotation-swizzled
// so B-fragments are aligned ds_read_b128. att A-frags read from global (L1/L2
// hot: 32 KB/batch shared by 128 blocks). LDS 35.8 KB -> 4 blocks/CU.
// grid 2048 = 16 batches x 128 n-chunks of 128, block 256
// ---------------------------------------------------------------------------
#define K3_LD 136   // k-extent 128 + 8 pad (272 B rows, 16B-aligned)
__global__ __launch_bounds__(256, 4) void k_out(const float* __restrict__ x,
                                                const u16* __restrict__ attb,
                                                const float* __restrict__ meanacc,
                                                const float* __restrict__ e2acc,
                                                const float* __restrict__ gamma,
                                                const float* __restrict__ bnw,
                                                const float* __restrict__ bnb,
                                                float* __restrict__ out)
{
    __shared__ u16 qT[128 * K3_LD];   // [n][k], k-group rotated by n
    __shared__ float alpha[128];
    __shared__ float beta[128];
    const int b   = blockIdx.x >> 7;
    const int nn0 = (blockIdx.x & 127) * 128;
    const int t   = threadIdx.x;

    if (t < 128) {
        float g   = gamma[0];
        const float invBN = 1.f / (float)(BB * NN);
        float m   = g * meanacc[t] * invBN;
        float e2  = g * g * e2acc[t] * invBN;
        float var = e2 - m * m;
        float inv = rsqrtf(var + BN_EPS);
        float wv  = bnw[t];
        alpha[t] = g * wv * inv;
        beta[t]  = bnb[t] - m * wv * inv;
    }

    const float* xb = x + (size_t)b * CC * NN + nn0;
    const int n0 = (t & 31) * 4;
#pragma unroll
    for (int rep = 0; rep < 4; ++rep) {
        const int c0 = ((t >> 5) + rep * 8) * 4;   // k-rows c0..c0+3
        float4 f0 = *(const float4*)(xb + (size_t)(c0 + 0) * NN + n0);
        float4 f1 = *(const float4*)(xb + (size_t)(c0 + 1) * NN + n0);
        float4 f2 = *(const float4*)(xb + (size_t)(c0 + 2) * NN + n0);
        float4 f3 = *(const float4*)(xb + (size_t)(c0 + 3) * NN + n0);
        const float fx[4] = {f0.x, f1.x, f2.x, f3.x};
        const float fy[4] = {f0.y, f1.y, f2.y, f3.y};
        const float fz[4] = {f0.z, f1.z, f2.z, f3.z};
        const float fw[4] = {f0.w, f1.w, f2.w, f3.w};
        const float* cols[4] = {fx, fy, fz, fw};
#pragma unroll
        for (int jn = 0; jn < 4; ++jn) {           // n = n0+jn: halfs k=c0..c0+3
            int n = n0 + jn;
            int g = ((c0 >> 3) + n) & 15;
            uint2 v;
            v.x = (unsigned)f2b(cols[jn][0]) | ((unsigned)f2b(cols[jn][1]) << 16);
            v.y = (unsigned)f2b(cols[jn][2]) | ((unsigned)f2b(cols[jn][3]) << 16);
            *(uint2*)&qT[n * K3_LD + g * 8 + (c0 & 7)] = v;
        }
    }
    __syncthreads();

    const int w = t >> 6, lane = t & 63, quad = lane >> 4, colL = lane & 15;
    const u16* ag = attb + (size_t)b * CC * CC;
    floatx4 acc[8][2];
#pragma unroll
    for (int rt = 0; rt < 8; ++rt) { acc[rt][0] = {0.f,0.f,0.f,0.f}; acc[rt][1] = {0.f,0.f,0.f,0.f}; }

#pragma unroll
    for (int ks = 0; ks < 4; ++ks) {
        const int kk = ks * 32 + quad * 8;
        const int n_a = w * 32 + colL;
        const int n_b = n_a + 16;
        short8 bf0 = *(const short8*)&qT[n_a * K3_LD + ((((kk) >> 3) + n_a) & 15) * 8];
        short8 bf1 = *(const short8*)&qT[n_b * K3_LD + ((((kk) >> 3) + n_b) & 15) * 8];
#pragma unroll
        for (int rt = 0; rt < 8; ++rt) {
            short8 af = *(const short8*)&ag[(rt * 16 + colL) * CC + kk];   // L1-hot
            acc[rt][0] = __builtin_amdgcn_mfma_f32_16x16x32_bf16(af, bf0, acc[rt][0], 0, 0, 0);
            acc[rt][1] = __builtin_amdgcn_mfma_f32_16x16x32_bf16(af, bf1, acc[rt][1], 0, 0, 0);
        }
    }

    float* ob = out + (size_t)b * CC * NN + nn0;
#pragma unroll
    for (int rt = 0; rt < 8; ++rt)
#pragma unroll
        for (int ct = 0; ct < 2; ++ct)
#pragma unroll
            for (int r = 0; r < 4; ++r) {
                int chn = rt * 16 + quad * 4 + r;
                int nn  = w * 32 + ct * 16 + colL;
                float v = alpha[chn] * acc[rt][ct][r] + beta[chn]
                        + xb[(size_t)chn * NN + nn];   // residual fp32 (L1-hot re-read)
                ob[(size_t)chn * NN + nn] = v;
            }
}

// ---------------------------------------------------------------------------
// ws layout (bytes):
//   [0,       1048576)  energy  fp32 [16][128][128]  (atomic-accumulated)
//   [1048576, 1056768)  S       fp32 [16][128]
//   [1056768, 1057280)  meanacc fp32 [128]
//   [1057280, 1057792)  e2acc   fp32 [128]
//   [1057792, 1582080)  attb    bf16 [16][128][128]
// ---------------------------------------------------------------------------
extern "C" void kernel_launch(void* const* d_in, const int* in_sizes, int n_in,
                              void* d_out, int out_size, void* d_ws, size_t ws_size,
                              hipStream_t stream)
{
    const float* x     = (const float*)d_in[0];
    const float* gamma = (const float*)d_in[1];
    const float* bnw   = (const float*)d_in[2];
    const float* bnb   = (const float*)d_in[3];
    float* out = (float*)d_out;

    char* ws = (char*)d_ws;
    float* energy  = (float*)(ws);
    float* S       = (float*)(ws + 1048576);
    float* meanacc = (float*)(ws + 1056768);
    float* e2acc   = (float*)(ws + 1057280);
    u16*   attb    = (u16*)(ws + 1057792);

    hipMemsetAsync(ws, 0, 1057792, stream);   // zero energy/S/accumulators
    hipLaunchKernelGGL(k_gram, dim3(512), dim3(512), 0, stream, x, energy, S);
    hipLaunchKernelGGL(k_soft, dim3(2048), dim3(256), 0, stream, energy, S, attb, meanacc, e2acc);
    hipLaunchKernelGGL(k_out,  dim3(2048), dim3(256), 0, stream, x, attb, meanacc, e2acc, gamma, bnw, bnb, out);
}